// Round 1
// baseline (311.538 us; speedup 1.0000x reference)
//
#include <hip/hip_runtime.h>
#include <hip/hip_bf16.h>
#include <stdint.h>

#define IN_F 1024
#define OUT_F 1024
#define NG 8
#define KSPLINE 8192            // IN_F * NG
#define KDIM 9216               // KSPLINE + IN_F
#define M_ROWS 8192
#define LOG2E 1.4426950408889634f
// KC = 1.75 * sqrt(log2(e)) : basis = exp(-((xn-c)*1.75)^2) = 2^(-(xn*KC - c*KC)^2)
#define KC 2.1019642153762872f

#define A_BLOCKS (M_ROWS / 4)           // 2048 (4 rows per block, wave-per-row)
#define W_BLOCKS ((OUT_F * 2304) / 256) // 9216

#define RB (KDIM * 2)                   // row bytes (18432)

using half4v = __attribute__((ext_vector_type(4))) _Float16;
using half8  = __attribute__((ext_vector_type(8))) _Float16;
using f32x4  = __attribute__((ext_vector_type(4))) float;

#define AS1 __attribute__((address_space(1)))
#define AS3 __attribute__((address_space(3)))

// ---- merged prep: blocks [0, A_BLOCKS) build A; [A_BLOCKS, +W_BLOCKS) build W
__global__ __launch_bounds__(256) void prep_kernel(
        const float* __restrict__ x, const float* __restrict__ gamma,
        const float* __restrict__ beta, const float* __restrict__ sw,
        const float* __restrict__ bw, _Float16* __restrict__ A,
        _Float16* __restrict__ W) {
    if (blockIdx.x >= A_BLOCKS) {
        int idx = (blockIdx.x - A_BLOCKS) * 256 + threadIdx.x;  // one float4 each
        int o   = idx / 2304;
        int k4  = idx - o * 2304;
        float4 v;
        if (k4 < 2048) v = ((const float4*)sw)[(size_t)o * 2048 + k4];
        else           v = ((const float4*)bw)[(size_t)o * 256 + (k4 - 2048)];
        half4v h = { (_Float16)v.x, (_Float16)v.y, (_Float16)v.z, (_Float16)v.w };
        *(half4v*)(W + (size_t)idx * 4) = h;
        return;
    }
    const int wave = threadIdx.x >> 6, lane = threadIdx.x & 63;
    const int row = blockIdx.x * 4 + wave;
    const float4* xr = (const float4*)(x + (size_t)row * IN_F);

    // lane owns features (j*64+lane)*4 .. +3 -> vectorized loads AND stores
    float4 xv[4];
    float s = 0.0f, s2 = 0.0f;
#pragma unroll
    for (int j = 0; j < 4; ++j) {
        float4 v = xr[j * 64 + lane];
        xv[j] = v;
        s  += v.x + v.y + v.z + v.w;
        s2 += v.x * v.x + v.y * v.y + v.z * v.z + v.w * v.w;
    }
#pragma unroll
    for (int off = 32; off > 0; off >>= 1) {
        s  += __shfl_xor(s, off);
        s2 += __shfl_xor(s2, off);
    }
    float mu   = s * (1.0f / IN_F);
    float var  = s2 * (1.0f / IN_F) - mu * mu;
    float rstd = rsqrtf(var + 1e-5f);

    const float cq[8] = {
        -2.0000000f * KC, -1.4285715f * KC, -0.8571429f * KC, -0.2857143f * KC,
         0.2857143f * KC,  0.8571429f * KC,  1.4285715f * KC,  2.0000000f * KC };

    _Float16* Arow = A + (size_t)row * KDIM;
    half8* basis_out = (half8*)Arow;                       // chunk f = feature f
    _Float16* silu_out = Arow + KSPLINE;
    const float4* g4 = (const float4*)gamma;
    const float4* b4 = (const float4*)beta;
#pragma unroll
    for (int j = 0; j < 4; ++j) {
        int idx = j * 64 + lane;
        float4 g = g4[idx], bt = b4[idx];
        float xs4[4] = { xv[j].x, xv[j].y, xv[j].z, xv[j].w };
        float gg4[4] = { g.x, g.y, g.z, g.w };
        float bb4[4] = { bt.x, bt.y, bt.z, bt.w };
        half4v sil;
#pragma unroll
        for (int c = 0; c < 4; ++c) {
            float xs = xs4[c];
            float xq = ((xs - mu) * rstd * gg4[c] + bb4[c]) * KC;
            half8 h;
#pragma unroll
            for (int gi = 0; gi < 8; ++gi) {
                float v = xq - cq[gi];
                h[gi] = (_Float16)exp2f(-(v * v));
            }
            basis_out[idx * 4 + c] = h;                    // 16B store, 64B/lane
            sil[c] = (_Float16)(xs / (1.0f + exp2f(-xs * LOG2E)));
        }
        *(half4v*)(silu_out + idx * 4) = sil;              // 8B store
    }
}

// ---------------- GEMM: C(8192 x 1024) = A(8192 x 9216) * W^T + bias ----------
// 256x128 tile, 8 waves (4M x 2N, per-wave 64x64), BK=64, double-buffered
// 96KB LDS. 4-phase schedule per K-tile with counted vmcnt(4) at the tile
// boundary ONLY (never 0 in main loop), raw s_barrier, setprio around MFMA
// clusters, and (row&7)<<4 XOR bank-swizzle applied as: linear global_load_lds
// dest + inverse-swizzled per-lane SOURCE addr + swizzled ds_read addr.
__global__ __launch_bounds__(512, 2) void gemm_kernel(
        const _Float16* __restrict__ A, const _Float16* __restrict__ W,
        const float* __restrict__ bias, float* __restrict__ C) {
    extern __shared__ __align__(16) char smem[];   // [A0 32K][A1 32K][B0 16K][B1 16K]
    const int tid  = threadIdx.x;
    const int wave = tid >> 6, lane = tid & 63;
    const int wm = wave >> 1, wn = wave & 1;       // 4M x 2N wave grid
    const int bm = blockIdx.x, bn = blockIdx.y;

    // ---- staging source (per-lane, pre-swizzled so linear LDS dest ends up swizzled)
    const int l8 = lane >> 3;                               // row-within-8, == (r&7)
    const int srcswz = ((lane & 7) ^ l8) << 4;              // 16B slot within 128B row
    const char* pA = (const char*)A + (size_t)(bm * 256 + wave * 32 + l8) * RB + srcswz;
    const char* pB = (const char*)W + (size_t)(bn * 128 + wave * 16 + l8) * RB + srcswz;
    const int dstA = wave * 4096;   // 4 chunks x 1024B per wave (32 chunks total)
    const int dstB = wave * 2048;   // 2 chunks x 1024B per wave (16 chunks total)

    // ---- ds_read offsets (swizzled) ----
    const int lm   = lane & 15;
    const int hi16 = (lane >> 4) << 4;                      // 0,16,32,48 (k-bytes)
    const int rowA = wm * 64 + lm;
    const int swzA = (rowA & 7) << 4;
    const int aoff0 = rowA * 128 + (hi16 ^ swzA);           // kh=0
    const int aoff1 = rowA * 128 + ((64 | hi16) ^ swzA);    // kh=1
    const int rowB = wn * 64 + lm;
    const int swzB = (rowB & 7) << 4;
    const int boff0 = rowB * 128 + (hi16 ^ swzB);
    const int boff1 = rowB * 128 + ((64 | hi16) ^ swzB);

    f32x4 acc[4][4] = {};

    // ---- prologue: stage tile 0 into buf0 (6 loads/wave) ----
#pragma unroll
    for (int j = 0; j < 4; ++j)
        __builtin_amdgcn_global_load_lds((const AS1 void*)(pA + (size_t)j * 8 * RB),
            (AS3 void*)(smem + dstA + j * 1024), 16, 0, 0);
#pragma unroll
    for (int j = 0; j < 2; ++j)
        __builtin_amdgcn_global_load_lds((const AS1 void*)(pB + (size_t)j * 8 * RB),
            (AS3 void*)(smem + 65536 + dstB + j * 1024), 16, 0, 0);

    const int NT = KDIM / 64;   // 144
    for (int kt = 0; kt < NT; ++kt) {
        const int cur = kt & 1;
        char* sA  = smem + cur * 32768;
        char* sAn = smem + (cur ^ 1) * 32768;
        char* sB  = smem + 65536 + cur * 16384;
        char* sBn = smem + 65536 + (cur ^ 1) * 16384;

        // ---- tile boundary: issue next A halves, counted wait, barrier ----
        if (kt + 1 < NT) {
            const char* pAn = pA + (size_t)(kt + 1) * 128;
#pragma unroll
            for (int j = 0; j < 4; ++j)
                __builtin_amdgcn_global_load_lds((const AS1 void*)(pAn + (size_t)j * 8 * RB),
                    (AS3 void*)(sAn + dstA + j * 1024), 16, 0, 0);
            asm volatile("s_waitcnt vmcnt(4)" ::: "memory");  // tile kt resident; 4 in flight
        } else {
            asm volatile("s_waitcnt vmcnt(0)" ::: "memory");  // final tile: drain
        }
        __builtin_amdgcn_s_barrier();

        // ---- phase 0: all B frags + A(mi=0); stage next B ----
        half8 b[4][2];
#pragma unroll
        for (int ni = 0; ni < 4; ++ni) {
            b[ni][0] = *(const half8*)(sB + (boff0 + ni * 2048));
            b[ni][1] = *(const half8*)(sB + (boff1 + ni * 2048));
        }
        half8 a0 = *(const half8*)(sA + aoff0);
        half8 a1 = *(const half8*)(sA + aoff1);
        if (kt + 1 < NT) {
            const char* pBn = pB + (size_t)(kt + 1) * 128;
#pragma unroll
            for (int j = 0; j < 2; ++j)
                __builtin_amdgcn_global_load_lds((const AS1 void*)(pBn + (size_t)j * 8 * RB),
                    (AS3 void*)(sBn + dstB + j * 1024), 16, 0, 0);
        }
        __builtin_amdgcn_s_barrier();
        asm volatile("s_waitcnt lgkmcnt(0)" ::: "memory");
        __builtin_amdgcn_sched_barrier(0);
        __builtin_amdgcn_s_setprio(1);
#pragma unroll
        for (int ni = 0; ni < 4; ++ni)
            acc[0][ni] = __builtin_amdgcn_mfma_f32_16x16x32_f16(a0, b[ni][0], acc[0][ni], 0, 0, 0);
#pragma unroll
        for (int ni = 0; ni < 4; ++ni)
            acc[0][ni] = __builtin_amdgcn_mfma_f32_16x16x32_f16(a1, b[ni][1], acc[0][ni], 0, 0, 0);
        __builtin_amdgcn_s_setprio(0);
        __builtin_amdgcn_s_barrier();

        // ---- phases 1..3: A(mi=p), reuse B frags ----
#pragma unroll
        for (int p = 1; p < 4; ++p) {
            half8 c0 = *(const half8*)(sA + (aoff0 + p * 2048));
            half8 c1 = *(const half8*)(sA + (aoff1 + p * 2048));
            __builtin_amdgcn_s_barrier();
            asm volatile("s_waitcnt lgkmcnt(0)" ::: "memory");
            __builtin_amdgcn_sched_barrier(0);
            __builtin_amdgcn_s_setprio(1);
#pragma unroll
            for (int ni = 0; ni < 4; ++ni)
                acc[p][ni] = __builtin_amdgcn_mfma_f32_16x16x32_f16(c0, b[ni][0], acc[p][ni], 0, 0, 0);
#pragma unroll
            for (int ni = 0; ni < 4; ++ni)
                acc[p][ni] = __builtin_amdgcn_mfma_f32_16x16x32_f16(c1, b[ni][1], acc[p][ni], 0, 0, 0);
            __builtin_amdgcn_s_setprio(0);
            __builtin_amdgcn_s_barrier();
        }
    }

    // epilogue: C/D layout col = lane&15, row = (lane>>4)*4 + reg
    const int cn  = lane & 15;
    const int rm4 = (lane >> 4) * 4;
#pragma unroll
    for (int ni = 0; ni < 4; ++ni) {
        int col = bn * 128 + wn * 64 + ni * 16 + cn;
        float bv = bias[col];
#pragma unroll
        for (int mi = 0; mi < 4; ++mi) {
            int row = bm * 256 + wm * 64 + mi * 16 + rm4;
            float* Cp = C + (size_t)row * OUT_F + col;
#pragma unroll
            for (int r = 0; r < 4; ++r)
                Cp[(size_t)r * OUT_F] = acc[mi][ni][r] + bv;
        }
    }
}

extern "C" void kernel_launch(void* const* d_in, const int* in_sizes, int n_in,
                              void* d_out, int out_size, void* d_ws, size_t ws_size,
                              hipStream_t stream) {
    const float* x     = (const float*)d_in[0];
    const float* gamma = (const float*)d_in[1];
    const float* beta  = (const float*)d_in[2];
    const float* sw    = (const float*)d_in[3];
    const float* bw    = (const float*)d_in[4];
    const float* bb    = (const float*)d_in[5];
    float* out = (float*)d_out;

    char* ws = (char*)d_ws;
    _Float16* Wb = (_Float16*)ws;                                 // 18.9 MB
    _Float16* Ab = (_Float16*)(ws + (size_t)OUT_F * KDIM * 2);    // 151 MB

    static int s_attr = 0;
    if (!s_attr) {
        hipFuncSetAttribute(reinterpret_cast<const void*>(gemm_kernel),
                            hipFuncAttributeMaxDynamicSharedMemorySize, 98304);
        s_attr = 1;
    }

    prep_kernel<<<A_BLOCKS + W_BLOCKS, 256, 0, stream>>>(
        x, gamma, beta, sw, bw, Ab, Wb);
    gemm_kernel<<<dim3(M_ROWS / 256, OUT_F / 128), 512, 98304, stream>>>(
        Ab, Wb, bb, out);
}

// Round 2
// 297.068 us; speedup vs baseline: 1.0487x; 1.0487x over previous
//
#include <hip/hip_runtime.h>
#include <hip/hip_bf16.h>
#include <stdint.h>

#define IN_F 1024
#define OUT_F 1024
#define NG 8
#define KSPLINE 8192            // IN_F * NG
#define KDIM 9216               // KSPLINE + IN_F
#define KHALF 4608              // split-K half (72 tiles of 64)
#define M_ROWS 8192
#define LOG2E 1.4426950408889634f
// KC = 1.75 * sqrt(log2(e)) : basis = exp(-((xn-c)*1.75)^2) = 2^(-(xn*KC - c*KC)^2)
#define KC 2.1019642153762872f

#define A_BLOCKS (M_ROWS / 4)           // 2048 (4 rows per block, wave-per-row)
#define W_BLOCKS ((OUT_F * 2304) / 256) // 9216
#define RB (KDIM * 2)                   // A/W row bytes (18432)

using half4v = __attribute__((ext_vector_type(4))) _Float16;
using half8  = __attribute__((ext_vector_type(8))) _Float16;
using f32x4  = __attribute__((ext_vector_type(4))) float;

#define AS1 __attribute__((address_space(1)))
#define AS3 __attribute__((address_space(3)))

// ---- merged prep (round-0 version: coalesced 16B basis stores) ----
__global__ __launch_bounds__(256) void prep_kernel(
        const float* __restrict__ x, const float* __restrict__ gamma,
        const float* __restrict__ beta, const float* __restrict__ sw,
        const float* __restrict__ bw, _Float16* __restrict__ A,
        _Float16* __restrict__ W) {
    if (blockIdx.x >= A_BLOCKS) {
        int idx = (blockIdx.x - A_BLOCKS) * 256 + threadIdx.x;  // one float4 each
        int o   = idx / 2304;
        int k4  = idx - o * 2304;
        float4 v;
        if (k4 < 2048) v = ((const float4*)sw)[(size_t)o * 2048 + k4];
        else           v = ((const float4*)bw)[(size_t)o * 256 + (k4 - 2048)];
        half4v h = { (_Float16)v.x, (_Float16)v.y, (_Float16)v.z, (_Float16)v.w };
        *(half4v*)(W + (size_t)idx * 4) = h;
        return;
    }
    const int wave = threadIdx.x >> 6, lane = threadIdx.x & 63;
    const int row = blockIdx.x * 4 + wave;
    const float* xr = x + (size_t)row * IN_F;

    float xv[16];
    float s = 0.0f, s2 = 0.0f;
#pragma unroll
    for (int j = 0; j < 16; ++j) {
        float v = xr[j * 64 + lane];
        xv[j] = v;
        s += v;
        s2 += v * v;
    }
#pragma unroll
    for (int off = 32; off > 0; off >>= 1) {
        s  += __shfl_xor(s, off);
        s2 += __shfl_xor(s2, off);
    }
    float mu   = s * (1.0f / IN_F);
    float var  = s2 * (1.0f / IN_F) - mu * mu;
    float rstd = rsqrtf(var + 1e-5f);

    const float cq[8] = {
        -2.0000000f * KC, -1.4285715f * KC, -0.8571429f * KC, -0.2857143f * KC,
         0.2857143f * KC,  0.8571429f * KC,  1.4285715f * KC,  2.0000000f * KC };

    _Float16* Arow = A + (size_t)row * KDIM;
    half8* basis_out = (half8*)Arow;                       // chunk f = feature f
    _Float16* silu_out = Arow + KSPLINE;
#pragma unroll
    for (int j = 0; j < 16; ++j) {
        int f = j * 64 + lane;
        float xs = xv[j];
        float xq = ((xs - mu) * rstd * gamma[f] + beta[f]) * KC;
        half8 h;
#pragma unroll
        for (int g = 0; g < 8; ++g) {
            float v = xq - cq[g];
            h[g] = (_Float16)exp2f(-(v * v));
        }
        basis_out[f] = h;
        silu_out[f] = (_Float16)(xs / (1.0f + exp2f(-xs * LOG2E)));
    }
}

// ---------------- GEMM: 256x256 block tile, per-wave 128x64 (reads/MFMA 0.375),
// 8 waves (2M x 4N), BK=64, double-buffered 128KB LDS, split-K=2.
// Per tile: boundary {issue 8 gload_lds for t+1, vmcnt(8), barrier} then 4
// phases {ds_read subtile; barrier; lgkmcnt(0); setprio(1); 16 MFMA;
// setprio(0); barrier}. Prefetch distance = 1 full tile (~3000cyc >> HBM lat).
// XOR-swizzle (row&7)<<4: linear gload dest + inverse-swizzled global source +
// swizzled ds_read (both-sides rule). Bijective XCD swizzle co-locates the 4
// bn-siblings of each (bm,z) A-panel (2.36MB < 4MB L2/XCD).
__global__ __launch_bounds__(512, 2) void gemm_kernel(
        const _Float16* __restrict__ A, const _Float16* __restrict__ W,
        const float* __restrict__ bias, float* __restrict__ C,
        float* __restrict__ P, int ntiles, int gpz) {
    extern __shared__ __align__(16) char smem[];   // 2 x [A 32K | B 32K]
    const int tid  = threadIdx.x;
    const int wave = tid >> 6, lane = tid & 63;
    const int wm = wave >> 2, wn = wave & 3;       // 2M x 4N wave grid

    // block swizzle: lb -> (xcd = lb&7, s = lb>>3); group g gets 4 bn-siblings
    const int lb = blockIdx.x;
    const int per_xcd = gridDim.x >> 5;            // groups per XCD (8 or 4)
    const int xcd = lb & 7, sl = lb >> 3;
    const int g  = xcd * per_xcd + (sl >> 2);
    const int bn = sl & 3;
    const int bm = g / gpz;
    const int z  = g - bm * gpz;

    // staging: instr j of wave covers rows j*64 + wave*8 + (lane>>3), slot lane&7
    const int l8 = lane >> 3;
    const int srcswz = ((lane & 7) ^ l8) << 4;     // inverse-swizzled source slot
    const char* pA = (const char*)A + (size_t)(bm * 256 + wave * 8 + l8) * RB
                     + (size_t)z * (KHALF * 2) + srcswz;
    const char* pB = (const char*)W + (size_t)(bn * 256 + wave * 8 + l8) * RB
                     + (size_t)z * (KHALF * 2) + srcswz;
    const int dstOff = wave * 1024;                // + j*8192 (+ lane*16 implicit)

    // ds_read offsets (swizzled); row&7 == lm&7 for all frags
    const int lm  = lane & 15;
    const int hi  = (lane >> 4) << 4;
    const int swz = (lm & 7) << 4;
    const int aoff0 = (wm * 128 + lm) * 128 + ((0  + hi) ^ swz);
    const int aoff1 = (wm * 128 + lm) * 128 + ((64 + hi) ^ swz);
    const int boff0 = 32768 + (wn * 64 + lm) * 128 + ((0  + hi) ^ swz);
    const int boff1 = 32768 + (wn * 64 + lm) * 128 + ((64 + hi) ^ swz);

    f32x4 acc[8][4] = {};

    // prologue: stage tile 0 into buf 0 (8 instrs/wave)
#pragma unroll
    for (int j = 0; j < 4; ++j) {
        __builtin_amdgcn_global_load_lds((const AS1 void*)(pA + (size_t)j * 64 * RB),
            (AS3 void*)(smem + j * 8192 + dstOff), 16, 0, 0);
        __builtin_amdgcn_global_load_lds((const AS1 void*)(pB + (size_t)j * 64 * RB),
            (AS3 void*)(smem + 32768 + j * 8192 + dstOff), 16, 0, 0);
    }

    for (int kt = 0; kt < ntiles; ++kt) {
        char* sbuf = smem + (kt & 1) * 65536;
        char* nbuf = smem + ((kt & 1) ^ 1) * 65536;

        // tile boundary: issue t+1 stage, counted wait (never 0 mid-loop)
        if (kt + 1 < ntiles) {
            const size_t kb = (size_t)(kt + 1) * 128;
#pragma unroll
            for (int j = 0; j < 4; ++j) {
                __builtin_amdgcn_global_load_lds((const AS1 void*)(pA + (size_t)j * 64 * RB + kb),
                    (AS3 void*)(nbuf + j * 8192 + dstOff), 16, 0, 0);
                __builtin_amdgcn_global_load_lds((const AS1 void*)(pB + (size_t)j * 64 * RB + kb),
                    (AS3 void*)(nbuf + 32768 + j * 8192 + dstOff), 16, 0, 0);
            }
            asm volatile("s_waitcnt vmcnt(8)" ::: "memory");  // tile kt resident
        } else {
            asm volatile("s_waitcnt vmcnt(0)" ::: "memory");
        }
        __builtin_amdgcn_s_barrier();

        // phase 0: all B frags + A(mf 0,1)
        half8 b[4][2];
#pragma unroll
        for (int nf = 0; nf < 4; ++nf) {
            b[nf][0] = *(const half8*)(sbuf + boff0 + nf * 2048);
            b[nf][1] = *(const half8*)(sbuf + boff1 + nf * 2048);
        }
        {
            half8 a00 = *(const half8*)(sbuf + aoff0);
            half8 a01 = *(const half8*)(sbuf + aoff1);
            half8 a10 = *(const half8*)(sbuf + aoff0 + 2048);
            half8 a11 = *(const half8*)(sbuf + aoff1 + 2048);
            __builtin_amdgcn_s_barrier();
            asm volatile("s_waitcnt lgkmcnt(0)" ::: "memory");
            __builtin_amdgcn_sched_barrier(0);
            __builtin_amdgcn_s_setprio(1);
#pragma unroll
            for (int nf = 0; nf < 4; ++nf) {
                acc[0][nf] = __builtin_amdgcn_mfma_f32_16x16x32_f16(a00, b[nf][0], acc[0][nf], 0, 0, 0);
                acc[1][nf] = __builtin_amdgcn_mfma_f32_16x16x32_f16(a10, b[nf][0], acc[1][nf], 0, 0, 0);
            }
#pragma unroll
            for (int nf = 0; nf < 4; ++nf) {
                acc[0][nf] = __builtin_amdgcn_mfma_f32_16x16x32_f16(a01, b[nf][1], acc[0][nf], 0, 0, 0);
                acc[1][nf] = __builtin_amdgcn_mfma_f32_16x16x32_f16(a11, b[nf][1], acc[1][nf], 0, 0, 0);
            }
            __builtin_amdgcn_s_setprio(0);
            __builtin_amdgcn_s_barrier();
        }
        // phases 1..3: A(mf 2p, 2p+1), reuse B frags
#pragma unroll
        for (int p = 1; p < 4; ++p) {
            half8 a00 = *(const half8*)(sbuf + aoff0 + (2 * p) * 2048);
            half8 a01 = *(const half8*)(sbuf + aoff1 + (2 * p) * 2048);
            half8 a10 = *(const half8*)(sbuf + aoff0 + (2 * p + 1) * 2048);
            half8 a11 = *(const half8*)(sbuf + aoff1 + (2 * p + 1) * 2048);
            __builtin_amdgcn_s_barrier();
            asm volatile("s_waitcnt lgkmcnt(0)" ::: "memory");
            __builtin_amdgcn_sched_barrier(0);
            __builtin_amdgcn_s_setprio(1);
#pragma unroll
            for (int nf = 0; nf < 4; ++nf) {
                acc[2*p][nf]   = __builtin_amdgcn_mfma_f32_16x16x32_f16(a00, b[nf][0], acc[2*p][nf], 0, 0, 0);
                acc[2*p+1][nf] = __builtin_amdgcn_mfma_f32_16x16x32_f16(a10, b[nf][0], acc[2*p+1][nf], 0, 0, 0);
            }
#pragma unroll
            for (int nf = 0; nf < 4; ++nf) {
                acc[2*p][nf]   = __builtin_amdgcn_mfma_f32_16x16x32_f16(a01, b[nf][1], acc[2*p][nf], 0, 0, 0);
                acc[2*p+1][nf] = __builtin_amdgcn_mfma_f32_16x16x32_f16(a11, b[nf][1], acc[2*p+1][nf], 0, 0, 0);
            }
            __builtin_amdgcn_s_setprio(0);
            __builtin_amdgcn_s_barrier();
        }
    }

    // epilogue: C/D layout col = lane&15, row = (lane>>4)*4 + reg
    const int cn  = lane & 15;
    const int rm4 = (lane >> 4) * 4;
    float* dst = z ? P : C;
#pragma unroll
    for (int nf = 0; nf < 4; ++nf) {
        int col = bn * 256 + wn * 64 + nf * 16 + cn;
        float bv = z ? 0.0f : bias[col];
#pragma unroll
        for (int mf = 0; mf < 8; ++mf) {
            int row = bm * 256 + wm * 128 + mf * 16 + rm4;
            float* cp = dst + (size_t)row * OUT_F + col;
#pragma unroll
            for (int r = 0; r < 4; ++r)
                cp[(size_t)r * OUT_F] = acc[mf][nf][r] + bv;
        }
    }
}

// ---- split-K reduction: C += P (C already holds partial0 + bias) ----
__global__ __launch_bounds__(256) void reduce_kernel(float* __restrict__ C,
        const float* __restrict__ P) {
    const int n4 = M_ROWS * OUT_F / 4;
    float4* c4 = (float4*)C;
    const float4* p4 = (const float4*)P;
    for (int i = blockIdx.x * 256 + threadIdx.x; i < n4; i += 2048 * 256) {
        float4 a = c4[i];
        float4 b = p4[i];
        a.x += b.x; a.y += b.y; a.z += b.z; a.w += b.w;
        c4[i] = a;
    }
}

extern "C" void kernel_launch(void* const* d_in, const int* in_sizes, int n_in,
                              void* d_out, int out_size, void* d_ws, size_t ws_size,
                              hipStream_t stream) {
    const float* x     = (const float*)d_in[0];
    const float* gamma = (const float*)d_in[1];
    const float* beta  = (const float*)d_in[2];
    const float* sw    = (const float*)d_in[3];
    const float* bw    = (const float*)d_in[4];
    const float* bb    = (const float*)d_in[5];
    float* out = (float*)d_out;

    char* ws = (char*)d_ws;
    size_t offW = 0;
    size_t offA = (size_t)OUT_F * KDIM * 2;                       // 18.9 MB
    size_t offP = offA + (size_t)M_ROWS * KDIM * 2;               // +151 MB
    size_t need = offP + (size_t)M_ROWS * OUT_F * 4;              // +33.5 MB
    _Float16* Wb = (_Float16*)(ws + offW);
    _Float16* Ab = (_Float16*)(ws + offA);
    float*    Pb = (float*)(ws + offP);
    const int split = (ws_size >= need);

    static int s_attr = 0;
    if (!s_attr) {
        hipFuncSetAttribute(reinterpret_cast<const void*>(gemm_kernel),
                            hipFuncAttributeMaxDynamicSharedMemorySize, 131072);
        s_attr = 1;
    }

    prep_kernel<<<A_BLOCKS + W_BLOCKS, 256, 0, stream>>>(
        x, gamma, beta, sw, bw, Ab, Wb);
    if (split) {
        gemm_kernel<<<256, 512, 131072, stream>>>(Ab, Wb, bb, out, Pb, KHALF / 64, 2);
        reduce_kernel<<<2048, 256, 0, stream>>>(out, Pb);
    } else {
        gemm_kernel<<<128, 512, 131072, stream>>>(Ab, Wb, bb, out, Pb, KDIM / 64, 1);
    }
}

// Round 3
// 287.834 us; speedup vs baseline: 1.0824x; 1.0321x over previous
//
#include <hip/hip_runtime.h>
#include <hip/hip_bf16.h>
#include <stdint.h>

#define IN_F 1024
#define OUT_F 1024
#define NG 8
#define KSPLINE 8192            // IN_F * NG
#define KDIM 9216               // KSPLINE + IN_F
#define KHALF 4608              // split-K half (72 tiles of 64)
#define M_ROWS 8192
#define LOG2E 1.4426950408889634f
// KC = 1.75 * sqrt(log2(e)) : basis = exp(-((xn-c)*1.75)^2) = 2^(-(xn*KC - c*KC)^2)
#define KC 2.1019642153762872f

#define A_BLOCKS (M_ROWS / 4)           // 2048 (4 rows per block, wave-per-row)
#define W_BLOCKS ((OUT_F * 2304) / 256) // 9216
#define RB (KDIM * 2)                   // A/W row bytes (18432)

using half4v = __attribute__((ext_vector_type(4))) _Float16;
using half8  = __attribute__((ext_vector_type(8))) _Float16;
using f32x4  = __attribute__((ext_vector_type(4))) float;

#define AS1 __attribute__((address_space(1)))
#define AS3 __attribute__((address_space(3)))

// ---- merged prep: blocks [0, A_BLOCKS) build A; [A_BLOCKS, +W_BLOCKS) build W
__global__ __launch_bounds__(256) void prep_kernel(
        const float* __restrict__ x, const float* __restrict__ gamma,
        const float* __restrict__ beta, const float* __restrict__ sw,
        const float* __restrict__ bw, _Float16* __restrict__ A,
        _Float16* __restrict__ W) {
    if (blockIdx.x >= A_BLOCKS) {
        int idx = (blockIdx.x - A_BLOCKS) * 256 + threadIdx.x;  // one float4 each
        int o   = idx / 2304;
        int k4  = idx - o * 2304;
        float4 v;
        if (k4 < 2048) v = ((const float4*)sw)[(size_t)o * 2048 + k4];
        else           v = ((const float4*)bw)[(size_t)o * 256 + (k4 - 2048)];
        half4v h = { (_Float16)v.x, (_Float16)v.y, (_Float16)v.z, (_Float16)v.w };
        *(half4v*)(W + (size_t)idx * 4) = h;
        return;
    }
    const int wave = threadIdx.x >> 6, lane = threadIdx.x & 63;
    const int row = blockIdx.x * 4 + wave;
    const float* xr = x + (size_t)row * IN_F;

    float xv[16];
    float s = 0.0f, s2 = 0.0f;
#pragma unroll
    for (int j = 0; j < 16; ++j) {
        float v = xr[j * 64 + lane];
        xv[j] = v;
        s += v;
        s2 += v * v;
    }
#pragma unroll
    for (int off = 32; off > 0; off >>= 1) {
        s  += __shfl_xor(s, off);
        s2 += __shfl_xor(s2, off);
    }
    float mu   = s * (1.0f / IN_F);
    float var  = s2 * (1.0f / IN_F) - mu * mu;
    float rstd = rsqrtf(var + 1e-5f);

    const float cq[8] = {
        -2.0000000f * KC, -1.4285715f * KC, -0.8571429f * KC, -0.2857143f * KC,
         0.2857143f * KC,  0.8571429f * KC,  1.4285715f * KC,  2.0000000f * KC };

    _Float16* Arow = A + (size_t)row * KDIM;
    half8* basis_out = (half8*)Arow;                       // chunk f = feature f
    _Float16* silu_out = Arow + KSPLINE;
#pragma unroll
    for (int j = 0; j < 16; ++j) {
        int f = j * 64 + lane;
        float xs = xv[j];
        float xq = ((xs - mu) * rstd * gamma[f] + beta[f]) * KC;
        half8 h;
#pragma unroll
        for (int g = 0; g < 8; ++g) {
            float v = xq - cq[g];
            h[g] = (_Float16)exp2f(-(v * v));
        }
        basis_out[f] = h;
        silu_out[f] = (_Float16)(xs / (1.0f + exp2f(-xs * LOG2E)));
    }
}

// ---------------- GEMM: 256x256 tile, 8 waves (2Mx4N, per-wave 128x64), BK=64,
// double-buffered 128KB LDS, split-K=2. m201-faithful 4-phase schedule:
// phases are C-quadrants (nh,mh); each phase: {ds_read 0/4/12 frags; counted
// vmcnt(2) wait; stage 2 slots of tile t+1; barrier; lgkmcnt(0); setprio(1);
// 16 MFMA; setprio(0); barrier}. Staging slots (64 rows) are consumed in
// issue order, every slot >= 3 phases old at consumption; vmcnt never 0
// mid-loop. XOR swizzle (row&7)<<4: linear gload dest + inverse-swizzled
// global source + swizzled ds_read (both-sides rule).
__global__ __launch_bounds__(512, 2) void gemm_kernel(
        const _Float16* __restrict__ A, const _Float16* __restrict__ W,
        const float* __restrict__ bias, float* __restrict__ C,
        float* __restrict__ P, int ntiles, int gpz) {
    extern __shared__ __align__(16) char smem[];   // 2 x [A 32K | B 32K]
    const int tid  = threadIdx.x;
    const int wave = tid >> 6, lane = tid & 63;
    const int wm = wave >> 2, wn = wave & 3;       // 2M x 4N wave grid

    // bijective XCD swizzle (grid % 8 == 0): 4 bn-siblings per group
    const int lb = blockIdx.x;
    const int per_xcd = gridDim.x >> 5;
    const int xcd = lb & 7, sl = lb >> 3;
    const int g  = xcd * per_xcd + (sl >> 2);
    const int bn = sl & 3;
    const int bm = g / gpz;
    const int z  = g - bm * gpz;

    // ---- staging sources: slot s covers 64 rows (8 per wave), lane chunk
    // pre-swizzled so linear LDS dest yields swizzled layout
    const int l8 = lane >> 3;
    const int chunkswz = ((lane & 7) ^ l8) << 4;
    const size_t zoff = (size_t)z * (KHALF * 2);
    // A slot->rowbase {0,128,64,192}: slots {0,1}=mh0 rows, {2,3}=mh1 rows
    // B slot->rowbase {0,128,32,160}: slots {0,1}=nh0 rows, {2,3}=nh1 rows
    const int gA[4] = {0, 128, 64, 192};
    const int gB[4] = {0, 128, 32, 160};
    const char* pA[4];
    const char* pB[4];
#pragma unroll
    for (int s = 0; s < 4; ++s) {
        pA[s] = (const char*)A + (size_t)(bm * 256 + gA[s] + wave * 8 + l8) * RB
                + zoff + chunkswz;
        pB[s] = (const char*)W + (size_t)(bn * 256 + gB[s] + (wave >> 2) * 64
                + (wave & 3) * 8 + l8) * RB + zoff + chunkswz;
    }

#define STAGE_A(s, nb, colb) __builtin_amdgcn_global_load_lds( \
        (const AS1 void*)(pA[s] + (colb)), \
        (AS3 void*)(smem + (nb) + (s) * 8192 + wave * 1024), 16, 0, 0)
#define STAGE_B(s, nb, colb) __builtin_amdgcn_global_load_lds( \
        (const AS1 void*)(pB[s] + (colb)), \
        (AS3 void*)(smem + (nb) + 32768 + (s) * 8192 + wave * 1024), 16, 0, 0)

    // ---- ds_read offsets (swizzled) ----
    const int lm  = lane & 15;
    const int hi  = (lane >> 4) << 4;
    const int swz = (lm & 7) << 4;
    const int ck0 = (0  + hi) ^ swz;               // kh0 chunk byte
    const int ck1 = (64 + hi) ^ swz;               // kh1
    const int aB0 = (0 + wm) * 8192 + lm * 128;    // mh0 slots; frag mf2 -> +mf2*2048
    const int aB1 = (2 + wm) * 8192 + lm * 128;    // mh1 slots
    const int bB0 = 32768 + (0 + (wn >> 1)) * 8192 + ((wn & 1) * 32 + lm) * 128;
    const int bB1 = 32768 + (2 + (wn >> 1)) * 8192 + ((wn & 1) * 32 + lm) * 128;

    f32x4 acc[8][4] = {};

    // ---- prologue: tile 0 into buf0, steady-state issue order ----
    STAGE_A(0, 0, 0); STAGE_A(1, 0, 0);
    STAGE_B(0, 0, 0); STAGE_B(1, 0, 0);
    STAGE_B(2, 0, 0); STAGE_B(3, 0, 0);
    STAGE_A(2, 0, 0); STAGE_A(3, 0, 0);
    asm volatile("s_waitcnt vmcnt(4)" ::: "memory");   // A0A1,B0B1 resident
    __builtin_amdgcn_s_barrier();

    for (int kt = 0; kt < ntiles; ++kt) {
        const int cb = (kt & 1) * 65536;
        const int nb = cb ^ 65536;
        const size_t col = (size_t)(kt + 1) * 128;
        const bool pref = (kt + 1 < ntiles);

        // ===== phase 0: mf0-3 x nf0-1 (reads A0A1+B0B1; stage A0A1(t+1)) =====
        half8 aF[4][2], bF[2][2];
#pragma unroll
        for (int m = 0; m < 4; ++m) {
            aF[m][0] = *(const half8*)(smem + cb + aB0 + m * 2048 + ck0);
            aF[m][1] = *(const half8*)(smem + cb + aB0 + m * 2048 + ck1);
        }
#pragma unroll
        for (int n = 0; n < 2; ++n) {
            bF[n][0] = *(const half8*)(smem + cb + bB0 + n * 2048 + ck0);
            bF[n][1] = *(const half8*)(smem + cb + bB0 + n * 2048 + ck1);
        }
        asm volatile("s_waitcnt vmcnt(2)" ::: "memory");   // B2B3(t) resident
        if (pref) { STAGE_A(0, nb, col); STAGE_A(1, nb, col); }
        asm volatile("s_waitcnt lgkmcnt(8)" ::: "memory"); // throttle (12 reads)
        __builtin_amdgcn_s_barrier();
        asm volatile("s_waitcnt lgkmcnt(0)" ::: "memory");
        __builtin_amdgcn_s_setprio(1);
#pragma unroll
        for (int n = 0; n < 2; ++n)
#pragma unroll
            for (int m = 0; m < 4; ++m)
                acc[m][n] = __builtin_amdgcn_mfma_f32_16x16x32_f16(aF[m][0], bF[n][0], acc[m][n], 0, 0, 0);
#pragma unroll
        for (int n = 0; n < 2; ++n)
#pragma unroll
            for (int m = 0; m < 4; ++m)
                acc[m][n] = __builtin_amdgcn_mfma_f32_16x16x32_f16(aF[m][1], bF[n][1], acc[m][n], 0, 0, 0);
        __builtin_amdgcn_s_setprio(0);
        __builtin_amdgcn_s_barrier();

        // ===== phase 1: mf0-3 x nf2-3 (reads B2B3; stage B0B1(t+1)) =====
        half8 bG[2][2];
#pragma unroll
        for (int n = 0; n < 2; ++n) {
            bG[n][0] = *(const half8*)(smem + cb + bB1 + n * 2048 + ck0);
            bG[n][1] = *(const half8*)(smem + cb + bB1 + n * 2048 + ck1);
        }
        if (pref) {
            asm volatile("s_waitcnt vmcnt(2)" ::: "memory");  // A2A3(t) resident
            STAGE_B(0, nb, col); STAGE_B(1, nb, col);
        } else {
            asm volatile("s_waitcnt vmcnt(0)" ::: "memory");
        }
        __builtin_amdgcn_s_barrier();
        asm volatile("s_waitcnt lgkmcnt(0)" ::: "memory");
        __builtin_amdgcn_s_setprio(1);
#pragma unroll
        for (int n = 0; n < 2; ++n)
#pragma unroll
            for (int m = 0; m < 4; ++m)
                acc[m][2 + n] = __builtin_amdgcn_mfma_f32_16x16x32_f16(aF[m][0], bG[n][0], acc[m][2 + n], 0, 0, 0);
#pragma unroll
        for (int n = 0; n < 2; ++n)
#pragma unroll
            for (int m = 0; m < 4; ++m)
                acc[m][2 + n] = __builtin_amdgcn_mfma_f32_16x16x32_f16(aF[m][1], bG[n][1], acc[m][2 + n], 0, 0, 0);
        __builtin_amdgcn_s_setprio(0);
        __builtin_amdgcn_s_barrier();

        // ===== phase 2: mf4-7 x nf0-1 (reads A2A3; stage B2B3(t+1)) =====
        half8 aG[4][2];
#pragma unroll
        for (int m = 0; m < 4; ++m) {
            aG[m][0] = *(const half8*)(smem + cb + aB1 + m * 2048 + ck0);
            aG[m][1] = *(const half8*)(smem + cb + aB1 + m * 2048 + ck1);
        }
        if (pref) { STAGE_B(2, nb, col); STAGE_B(3, nb, col); }
        __builtin_amdgcn_s_barrier();
        asm volatile("s_waitcnt lgkmcnt(0)" ::: "memory");
        __builtin_amdgcn_s_setprio(1);
#pragma unroll
        for (int n = 0; n < 2; ++n)
#pragma unroll
            for (int m = 0; m < 4; ++m)
                acc[4 + m][n] = __builtin_amdgcn_mfma_f32_16x16x32_f16(aG[m][0], bF[n][0], acc[4 + m][n], 0, 0, 0);
#pragma unroll
        for (int n = 0; n < 2; ++n)
#pragma unroll
            for (int m = 0; m < 4; ++m)
                acc[4 + m][n] = __builtin_amdgcn_mfma_f32_16x16x32_f16(aG[m][1], bF[n][1], acc[4 + m][n], 0, 0, 0);
        __builtin_amdgcn_s_setprio(0);
        __builtin_amdgcn_s_barrier();

        // ===== phase 3: mf4-7 x nf2-3 (no reads; stage A2A3(t+1)) =====
        if (pref) {
            asm volatile("s_waitcnt vmcnt(2)" ::: "memory");  // A0A1,B0B1(t+1) resident
            STAGE_A(2, nb, col); STAGE_A(3, nb, col);
        }
        __builtin_amdgcn_s_barrier();
        __builtin_amdgcn_s_setprio(1);
#pragma unroll
        for (int n = 0; n < 2; ++n)
#pragma unroll
            for (int m = 0; m < 4; ++m)
                acc[4 + m][2 + n] = __builtin_amdgcn_mfma_f32_16x16x32_f16(aG[m][0], bG[n][0], acc[4 + m][2 + n], 0, 0, 0);
#pragma unroll
        for (int n = 0; n < 2; ++n)
#pragma unroll
            for (int m = 0; m < 4; ++m)
                acc[4 + m][2 + n] = __builtin_amdgcn_mfma_f32_16x16x32_f16(aG[m][1], bG[n][1], acc[4 + m][2 + n], 0, 0, 0);
        __builtin_amdgcn_s_setprio(0);
        __builtin_amdgcn_s_barrier();
    }

    // epilogue: C/D layout col = lane&15, row = (lane>>4)*4 + reg
    const int cn  = lane & 15;
    const int rm4 = (lane >> 4) * 4;
    float* dst = z ? P : C;
#pragma unroll
    for (int nf = 0; nf < 4; ++nf) {
        int col = bn * 256 + wn * 64 + nf * 16 + cn;
        float bv = z ? 0.0f : bias[col];
#pragma unroll
        for (int mf = 0; mf < 8; ++mf) {
            int row = bm * 256 + wm * 128 + mf * 16 + rm4;
            float* cp = dst + (size_t)row * OUT_F + col;
#pragma unroll
            for (int r = 0; r < 4; ++r)
                cp[(size_t)r * OUT_F] = acc[mf][nf][r] + bv;
        }
    }
}

// ---- split-K reduction: C += P (C already holds partial0 + bias) ----
__global__ __launch_bounds__(256) void reduce_kernel(float* __restrict__ C,
        const float* __restrict__ P) {
    const int n4 = M_ROWS * OUT_F / 4;
    float4* c4 = (float4*)C;
    const float4* p4 = (const float4*)P;
    for (int i = blockIdx.x * 256 + threadIdx.x; i < n4; i += 2048 * 256) {
        float4 a = c4[i];
        float4 b = p4[i];
        a.x += b.x; a.y += b.y; a.z += b.z; a.w += b.w;
        c4[i] = a;
    }
}

extern "C" void kernel_launch(void* const* d_in, const int* in_sizes, int n_in,
                              void* d_out, int out_size, void* d_ws, size_t ws_size,
                              hipStream_t stream) {
    const float* x     = (const float*)d_in[0];
    const float* gamma = (const float*)d_in[1];
    const float* beta  = (const float*)d_in[2];
    const float* sw    = (const float*)d_in[3];
    const float* bw    = (const float*)d_in[4];
    const float* bb    = (const float*)d_in[5];
    float* out = (float*)d_out;

    char* ws = (char*)d_ws;
    size_t offW = 0;
    size_t offA = (size_t)OUT_F * KDIM * 2;                       // 18.9 MB
    size_t offP = offA + (size_t)M_ROWS * KDIM * 2;               // +151 MB
    size_t need = offP + (size_t)M_ROWS * OUT_F * 4;              // +33.5 MB
    _Float16* Wb = (_Float16*)(ws + offW);
    _Float16* Ab = (_Float16*)(ws + offA);
    float*    Pb = (float*)(ws + offP);
    const int split = (ws_size >= need);

    static int s_attr = 0;
    if (!s_attr) {
        hipFuncSetAttribute(reinterpret_cast<const void*>(gemm_kernel),
                            hipFuncAttributeMaxDynamicSharedMemorySize, 131072);
        s_attr = 1;
    }

    prep_kernel<<<A_BLOCKS + W_BLOCKS, 256, 0, stream>>>(
        x, gamma, beta, sw, bw, Ab, Wb);
    if (split) {
        gemm_kernel<<<256, 512, 131072, stream>>>(Ab, Wb, bb, out, Pb, KHALF / 64, 2);
        reduce_kernel<<<2048, 256, 0, stream>>>(out, Pb);
    } else {
        gemm_kernel<<<128, 512, 131072, stream>>>(Ab, Wb, bb, out, Pb, KDIM / 64, 1);
    }
}